// Round 3
// baseline (49.168 us; speedup 1.0000x reference)
//
#include <hip/hip_runtime.h>

// x: [B=8, C=3, T=32, H=224, W=224] float32.
// out[b,c,t,h,w] = (w - tx[t] >= 0) ? x[b,c,t,h, w - tx[t]] : 0
// tx[t] = trunc(0.08 * |t - 16| * 224) = (2240 * dist) / 125  (exact integer form)

#define TT 32
#define HH 224
#define WW 224
#define W4 56   // WW / 4

typedef float f4 __attribute__((ext_vector_type(4)));  // native vector: ok for nontemporal builtins

__global__ __launch_bounds__(256) void shift_kernel(const float* __restrict__ in,
                                                    float* __restrict__ out,
                                                    int nvec /* total float4s */) {
    const int v = blockIdx.x * blockDim.x + threadIdx.x;
    if (v >= nvec) return;

    const int w4  = v % W4;          // float4 index within row
    const int row = v / W4;          // global row over B*C*T*H (fits 32-bit)
    const int t   = (row / HH) % TT; // frame index

    int dist = t - 16; if (dist < 0) dist = -dist;
    const int tx = (2240 * dist) / 125;   // exact trunc(17.92 * dist)

    f4 o = {0.f, 0.f, 0.f, 0.f};
    if (tx < WW) {
        // 32-bit element offsets: max index 38.5M < 2^31
        const float* __restrict__ rowp = in + row * WW;
        const int s = w4 * 4 - tx;   // source column of first element
        if (s >= 0) {
            o.x = __builtin_nontemporal_load(rowp + s + 0);
            o.y = __builtin_nontemporal_load(rowp + s + 1);
            o.z = __builtin_nontemporal_load(rowp + s + 2);
            o.w = __builtin_nontemporal_load(rowp + s + 3);
        } else {
            if (s + 0 >= 0) o.x = __builtin_nontemporal_load(rowp + s + 0);
            if (s + 1 >= 0) o.y = __builtin_nontemporal_load(rowp + s + 1);
            if (s + 2 >= 0) o.z = __builtin_nontemporal_load(rowp + s + 2);
            if (s + 3 >= 0) o.w = __builtin_nontemporal_load(rowp + s + 3);
        }
    }
    __builtin_nontemporal_store(o, reinterpret_cast<f4*>(out) + v);
}

extern "C" void kernel_launch(void* const* d_in, const int* in_sizes, int n_in,
                              void* d_out, int out_size, void* d_ws, size_t ws_size,
                              hipStream_t stream) {
    const float* x = (const float*)d_in[0];
    float* out = (float*)d_out;

    const int nvec = out_size / 4;             // 9,633,792
    const int blocks = (nvec + 255) / 256;     // 37,632 (exact)

    shift_kernel<<<blocks, 256, 0, stream>>>(x, out, nvec);
}

// Round 4
// 37.702 us; speedup vs baseline: 1.3041x; 1.3041x over previous
//
#include <hip/hip_runtime.h>

// x: [B=8, C=3, T=32, H=224, W=224] float32.
// out[b,c,t,h,w] = (w - tx[t] >= 0) ? x[b,c,t,h, w - tx[t]] : 0
// tx[t] = trunc(0.08 * |t - 16| * 224) = (2240 * dist) / 125  (exact integer form)

#define TT 32
#define HH 224
#define WW 224
#define W4 56   // WW / 4

typedef float f4 __attribute__((ext_vector_type(4)));

__global__ __launch_bounds__(256) void shift_kernel(const float* __restrict__ in,
                                                    float* __restrict__ out,
                                                    int nvec /* total float4s */) {
    const int stride = gridDim.x * blockDim.x;
    for (int v = blockIdx.x * blockDim.x + threadIdx.x; v < nvec; v += stride) {
        const int w4  = v % W4;          // float4 index within row
        const int row = v / W4;          // global row over B*C*T*H
        const int t   = (row / HH) % TT; // frame index

        int dist = t - 16; if (dist < 0) dist = -dist;
        const int tx = (2240 * dist) / 125;   // exact trunc(17.92 * dist)

        f4 o = {0.f, 0.f, 0.f, 0.f};
        if (tx < WW) {
            const float* __restrict__ rowp = in + row * WW;  // 32-bit offsets ok
            const int s = w4 * 4 - tx;   // source column of first element
            if (s >= 0) {
                // common path: one unaligned (dword-aligned) 16B vector load
                __builtin_memcpy(&o, rowp + s, sizeof(f4));
            } else if (s > -4) {
                // boundary float4 (at most one per row): partial scalar loads
                if (s + 1 >= 0) o.y = rowp[s + 1];
                if (s + 2 >= 0) o.z = rowp[s + 2];
                if (s + 3 >= 0) o.w = rowp[s + 3];
            }
            // s <= -4: fully out of range -> stays zero, no loads
        }
        reinterpret_cast<f4*>(out)[v] = o;
    }
}

extern "C" void kernel_launch(void* const* d_in, const int* in_sizes, int n_in,
                              void* d_out, int out_size, void* d_ws, size_t ws_size,
                              hipStream_t stream) {
    const float* x = (const float*)d_in[0];
    float* out = (float*)d_out;

    const int nvec = out_size / 4;   // 9,633,792
    int blocks = (nvec + 255) / 256;
    if (blocks > 2048) blocks = 2048;

    shift_kernel<<<blocks, 256, 0, stream>>>(x, out, nvec);
}

// Round 5
// 37.301 us; speedup vs baseline: 1.3182x; 1.0108x over previous
//
#include <hip/hip_runtime.h>

// x: [B=8, C=3, T=32, H=224, W=224] float32.
// out[b,c,t,h,w] = (w - tx[t] >= 0) ? x[b,c,t,h, w - tx[t]] : 0
// tx[t] = trunc(0.08 * |t - 16| * 224) = (2240 * dist) / 125  (exact integer form)
//
// Launch geometry does the indexing:
//   block = (56, 8)  -> 448 threads = 7 full waves; threadIdx.x = w4, threadIdx.y = h sub-row
//   grid  = (28, 768) -> blockIdx.x = h chunk (28*8 = 224 = H), blockIdx.y = plane (b*C+c)*T + t
// t = plane & 31 (T = 32), tx is block-uniform (SGPR), branch wave-uniform.

#define TT 32
#define HH 224
#define WW 224
#define W4 56   // WW / 4

typedef float f4 __attribute__((ext_vector_type(4)));

__global__ __launch_bounds__(448) void shift_kernel(const float* __restrict__ in,
                                                    float* __restrict__ out) {
    const int plane = blockIdx.y;               // 0..767
    const int t     = plane & (TT - 1);         // frame index (T = 32, pow2)

    int dist = t - 16; if (dist < 0) dist = -dist;
    const int tx = (2240 * dist) / 125;         // exact trunc(17.92 * dist), scalar

    const int h   = blockIdx.x * 8 + threadIdx.y;
    const int w4  = threadIdx.x;
    const int row = plane * HH + h;             // global row, fits 32-bit
    const int v   = row * W4 + w4;              // output float4 index

    f4 o = {0.f, 0.f, 0.f, 0.f};
    if (tx < WW) {                              // wave-uniform: zero frames skip loads
        const float* __restrict__ rowp = in + row * WW;
        const int s = w4 * 4 - tx;              // source column of first element
        if (s >= 0) {
            __builtin_memcpy(&o, rowp + s, sizeof(f4));   // one unaligned 16B load
        } else if (s > -4) {
            // boundary float4 (exactly one per row since tx % 4 != 0)
            if (s + 1 >= 0) o.y = rowp[s + 1];
            if (s + 2 >= 0) o.z = rowp[s + 2];
            if (s + 3 >= 0) o.w = rowp[s + 3];
        }
    }
    reinterpret_cast<f4*>(out)[v] = o;
}

extern "C" void kernel_launch(void* const* d_in, const int* in_sizes, int n_in,
                              void* d_out, int out_size, void* d_ws, size_t ws_size,
                              hipStream_t stream) {
    const float* x = (const float*)d_in[0];
    float* out = (float*)d_out;

    dim3 block(W4, 8, 1);        // 448 threads = 7 waves
    dim3 grid(HH / 8, 768, 1);   // 28 x (B*C*T)

    shift_kernel<<<grid, block, 0, stream>>>(x, out);
}